// Round 5
// baseline (94.345 us; speedup 1.0000x reference)
//
#include <hip/hip_runtime.h>

#define N_PARTS 62
#define M_SAMP  512
#define D_DIM   256
#define MARGIN  0.2f
#define ROWS    (N_PARTS * M_SAMP)   // 31744
#define PART_ELEMS (M_SAMP * D_DIM)  // 131072 bf16 per part

typedef unsigned short ushort_t;
typedef __attribute__((ext_vector_type(8))) short bf16x8;   // 8 bf16 = 4 VGPRs
typedef __attribute__((ext_vector_type(4))) float f32x4;

__device__ __forceinline__ ushort_t bf16_rne(float f) {
    unsigned u = __float_as_uint(f);
    unsigned r = u + 0x7fffu + ((u >> 16) & 1u);
    return (ushort_t)(r >> 16);
}

// K1, coalesced-store revision. R4 post-mortem: old prep's frag-major store
// scattered each wave-store into 32 x 16B segments on 32 distinct lines
// (~4x L2 transactions on 16.25 MB) -> prep ran ~2x its HBM roofline.
// New structure: wave = one 16-row frag group (g). Loads: 16 coalesced
// 1KB row-loads. Stage converted ushort4 pairs in a per-wave LDS region
// (c-stride 520 shorts: <=4-way bank aliasing, negligible), then write the
// 8 frag blocks as 8 perfectly-coalesced 1KB dwordx4 stores (every 64B
// line fully covered by a single instruction). Output layout and rounding
// are bit-identical to the verified baseline prep; gram is unchanged.
__global__ __launch_bounds__(256) void prep_kernel(const float* __restrict__ feat,
                                                   ushort_t* __restrict__ Fb,
                                                   float* __restrict__ sq,
                                                   float* __restrict__ out) {
    const int id = blockIdx.x;        // 0..495
    const int n  = id >> 3;           // part (0..61)
    const int gb = id & 7;            // 64-row slab within part
    if (id == 0 && threadIdx.x < 2 * N_PARTS) out[threadIdx.x] = 0.0f;
    const int wv   = threadIdx.x >> 6;            // wave -> one 16-row g-group
    const int lane = threadIdx.x & 63;
    const int g    = gb * 4 + wv;                 // frag group (0..31)

    // staging layout (shorts, per wave): [c:520][q:128][r:8][h:4]
    __shared__ ushort_t st[4][4160];
    ushort_t* W = st[wv];

    const int c = lane >> 3;          // k-chunk (0..7)
    const int q = (lane >> 1) & 3;    // 8-k quad within chunk
    const int h = lane & 1;           // 4-k half within quad
    const float* fb = feat + (size_t)(n * M_SAMP + g * 16) * D_DIM;

    #pragma unroll 4
    for (int i = 0; i < 16; ++i) {
        const float4 v = ((const float4*)(fb + (size_t)i * D_DIM))[lane];
        ushort4 us;
        us.x = bf16_rne(v.x); us.y = bf16_rne(v.y);
        us.z = bf16_rne(v.z); us.w = bf16_rne(v.w);
        const float fx = __uint_as_float((unsigned)us.x << 16);
        const float fy = __uint_as_float((unsigned)us.y << 16);
        const float fz = __uint_as_float((unsigned)us.z << 16);
        const float fw = __uint_as_float((unsigned)us.w << 16);
        *(ushort4*)(&W[c * 520 + q * 128 + i * 8 + h * 4]) = us;
        float ss = fx * fx + fy * fy + fz * fz + fw * fw;
        #pragma unroll
        for (int off = 32; off > 0; off >>= 1) ss += __shfl_xor(ss, off);
        if (lane == 0) sq[n * M_SAMP + g * 16 + i] = ss;
    }
    // wave-local write->read: lgkmcnt handled by compiler, no barrier needed
    // (each wave reads only its own region).
    const int rr = lane & 15;         // frag-lane row
    const int qq = lane >> 4;         // frag-lane quad
    ushort_t* outp = Fb + (size_t)n * PART_ELEMS + (size_t)g * 512 + lane * 8;
    #pragma unroll
    for (int fc = 0; fc < 8; ++fc) {
        const uint4 w = *(const uint4*)(&W[fc * 520 + qq * 128 + rr * 8]);
        *(uint4*)(outp + (size_t)fc * (32 * 512)) = w;
    }
}

// K2 (unchanged from R4, spill-free): 64x64 per-wave tile (acc[4][4] = 64
// regs), 64-col slabs (grid 8x64, XCD affinity id%8==n%8), B fragments
// streamed one at a time. Main-loop demand ~110 < the 128-VGPR budget the
// backend pins for this shape (R1-R3 post-mortem).
__global__ __launch_bounds__(512)
__attribute__((amdgpu_waves_per_eu(2, 4)))
void gram_kernel(const ushort_t* __restrict__ Fb, const float* __restrict__ sq,
                 float* __restrict__ out) {
    const int id = blockIdx.x;
    const int n  = id & 63;          // part (XCD affinity: id%8 == n%8)
    const int ct = id >> 6;          // col-slab (64 cols, 0..7)
    if (n >= N_PARTS) return;
    const int tid  = threadIdx.x;
    const int wave = tid >> 6, lane = tid & 63;
    const ushort_t* F = Fb + (size_t)n * PART_ELEMS;
    const float* SQ = sq + n * M_SAMP;

    __shared__ float mrg[8][64][3];   // [wave][slab-local col][hp,hn,ds]

    const ushort_t* aptr = F + (size_t)(wave * 4) * 512 + lane * 8;  // rows w*64..
    const ushort_t* bptr = F + (size_t)(ct * 4) * 512 + lane * 8;    // 64 slab cols

    f32x4 acc[4][4] = {};

    #pragma unroll
    for (int c = 0; c < 8; ++c) {
        const size_t off = (size_t)c * (32 * 512);
        bf16x8 af[4];
        #pragma unroll
        for (int i = 0; i < 4; ++i)
            af[i] = *(const bf16x8*)(aptr + off + (size_t)i * 512);
        // stream B fragments: one live at a time (8 regs, not 32)
        #pragma unroll
        for (int ni = 0; ni < 4; ++ni) {
            const bf16x8 bfv = *(const bf16x8*)(bptr + off + (size_t)ni * 512);
            #pragma unroll
            for (int mi = 0; mi < 4; ++mi)
                acc[mi][ni] = __builtin_amdgcn_mfma_f32_16x16x32_bf16(
                    af[mi], bfv, acc[mi][ni], 0, 0, 0);
        }
    }

    // Epilogue (verified R12 structure). C/D layout: col = lane&15,
    // row = (lane>>4)*4 + reg.
    float sqr[4][4];
    #pragma unroll
    for (int mi = 0; mi < 4; ++mi)
        #pragma unroll
        for (int p = 0; p < 4; ++p)
            sqr[mi][p] = SQ[wave * 64 + mi * 16 + (lane >> 4) * 4 + p];

    #pragma unroll
    for (int ni = 0; ni < 4; ++ni) {
        const int C = ct * 64 + ni * 16 + (lane & 15);     // part-local col
        const float sc = SQ[C];
        const int Cg = C >> 3;                             // label = m>>3
        float ds = 0.f, hp = 0.f, hn = 1e30f;
        #pragma unroll
        for (int mi = 0; mi < 4; ++mi) {
            #pragma unroll
            for (int p = 0; p < 4; ++p) {
                const int R = wave * 64 + mi * 16 + (lane >> 4) * 4 + p;
                const float d2 = sqr[mi][p] + sc - 2.f * acc[mi][ni][p];
                const float d  = __builtin_amdgcn_sqrtf(fmaxf(d2, 0.f));
                ds += d;
                if ((R >> 3) == Cg) hp = fmaxf(hp, d);
                else                hn = fminf(hn, d);
            }
        }
        // combine the 4 quads (same col, disjoint row subsets)
        #pragma unroll
        for (int off = 16; off < 64; off <<= 1) {
            ds += __shfl_xor(ds, off);
            hp = fmaxf(hp, __shfl_xor(hp, off));
            hn = fminf(hn, __shfl_xor(hn, off));
        }
        if (lane < 16) {
            mrg[wave][ni * 16 + lane][0] = hp;
            mrg[wave][ni * 16 + lane][1] = hn;
            mrg[wave][ni * 16 + lane][2] = ds;
        }
    }
    __syncthreads();
    if (tid < 64) {   // col tid of the slab: merge 8 row-strips, then reduce
        float hp = 0.f, hn = 1e30f, bd = 0.f;
        #pragma unroll
        for (int w = 0; w < 8; ++w) {
            hp = fmaxf(hp, mrg[w][tid][0]);
            hn = fminf(hn, mrg[w][tid][1]);
            bd += mrg[w][tid][2];
        }
        float bl = fmaxf(MARGIN + hp - hn, 0.f);
        #pragma unroll
        for (int off = 32; off > 0; off >>= 1) {
            bl += __shfl_xor(bl, off);
            bd += __shfl_xor(bd, off);
        }
        if (tid == 0) {
            atomicAdd(&out[n],           bl * (1.0f / 512.0f));
            atomicAdd(&out[N_PARTS + n], bd * (1.0f / (512.0f * 512.0f)));
        }
    }
}

extern "C" void kernel_launch(void* const* d_in, const int* in_sizes, int n_in,
                              void* d_out, int out_size, void* d_ws, size_t ws_size,
                              hipStream_t stream) {
    const float* feat = (const float*)d_in[0];    // [62, 512, 256] fp32
    float* out = (float*)d_out;                   // [124]

    ushort_t* Fb = (ushort_t*)d_ws;                                   // frag-major bf16
    float* sq    = (float*)((char*)d_ws + (size_t)ROWS * D_DIM * 2);  // row sum-of-squares

    prep_kernel<<<dim3(62 * 8), 256, 0, stream>>>(feat, Fb, sq, out);
    gram_kernel<<<dim3(8 * 64), 512, 0, stream>>>(Fb, sq, out);
}